// Round 3
// baseline (1311.305 us; speedup 1.0000x reference)
//
#include <hip/hip_runtime.h>
#include <cstdint>
#include <cstddef>

// ---------------------------------------------------------------------------
// RQ-VAE forward. All matmuls on MFMA via 2-term f16 split (hi + lo*2048):
// chains hh / h*lo / lo*h, cross-accumulator scaled 1/2048 at epilogue
// (keeps lo in normal f16 range -> no denorm-flush hazard). ~2^-22 relative
// precision: safe for codebook argmins. All GEMM operands are PRE-SPLIT
// (producer epilogues / prep kernels), so the GEMM main loop is pure
// global_load_lds + ds_read + MFMA, double-buffered 2-phase.
// RQ bookkeeping (argmin, residual, loss) stays exact fp32.
// ---------------------------------------------------------------------------

typedef _Float16 F16;
typedef F16   v8h  __attribute__((ext_vector_type(8)));
typedef F16   v2h  __attribute__((ext_vector_type(2)));
typedef F16   v4h  __attribute__((ext_vector_type(4)));
typedef float v4f  __attribute__((ext_vector_type(4)));

__device__ __forceinline__ void gload_lds16(const void* g, void* l) {
    __builtin_amdgcn_global_load_lds(
        (const __attribute__((address_space(1))) void*)g,
        (__attribute__((address_space(3))) void*)l, 16, 0, 0);
}

__device__ __forceinline__ void split2(float v, F16& h, F16& l) {
    h = (F16)v;
    l = (F16)((v - (float)h) * 2048.0f);   // lo scaled into normal f16 range
}

// ---------------------------------------------------------------------------
// C = act(A @ B^T + bias). A: M x K split (Ah/Al f16 row-major). B: N x K
// split. Tile 128x128, BK=32, 4 waves (2x2), 64x64/wave = 4x4 frags of
// 16x16x32_f16, 3 MFMA chains. Double-buffered LDS, 2-phase pipeline.
// LDS tile: [row 0..127][phys chunk 0..7] of 16B, phys = logical ^ (row&7);
// logical 0-3 = hi k0..31, 4-7 = lo. Linear dest for global_load_lds, with
// inverse-swizzled per-lane global source; frag reads use the same XOR.
// Grid: 1-D, XCD-bijective swizzle, N-inner (A-panel L2 locality).
// ---------------------------------------------------------------------------
template<bool RELU, bool HASBIAS, bool WF32, bool WSPLIT>
__global__ __launch_bounds__(256, 2)
void f16gemm2(const F16* __restrict__ Ah, const F16* __restrict__ Al,
              const F16* __restrict__ Bh, const F16* __restrict__ Bl,
              const float* __restrict__ bias,
              float* __restrict__ C, F16* __restrict__ Ch, F16* __restrict__ Cl,
              int N, int K, int nbn)
{
    __shared__ v8h As[2048];   // 2 bufs x (128 rows x 8 chunks) = 32 KB
    __shared__ v8h Bs[2048];

    const int tid  = threadIdx.x;
    const int lane = tid & 63;
    const int wid  = tid >> 6;

    // XCD-bijective swizzle (gridDim.x % 8 == 0 always here), N-inner.
    const int nb  = gridDim.x;
    const int cpx = nb >> 3;
    const int sw  = (blockIdx.x & 7) * cpx + (blockIdx.x >> 3);
    const int mt  = sw / nbn;
    const int nt_ = sw - mt * nbn;
    const long bm = (long)mt * 128;
    const long bn = (long)nt_ * 128;

    // ---- staging: wave w covers rows [32w, 32w+32), 4 gload_lds per operand
    const int rr = lane >> 3;              // row within 8-row group
    const int c  = (lane & 7) ^ rr;        // logical chunk this lane fetches
    const F16* aS[4]; const F16* bS[4];
    int dOf[4];
    #pragma unroll
    for (int jj = 0; jj < 4; jj++) {
        int rloc = wid * 32 + jj * 8;
        long ag = bm + rloc + rr, bg = bn + rloc + rr;
        aS[jj] = (c < 4) ? (Ah + ag * (long)K + c * 8) : (Al + ag * (long)K + (c - 4) * 8);
        bS[jj] = (c < 4) ? (Bh + bg * (long)K + c * 8) : (Bl + bg * (long)K + (c - 4) * 8);
        dOf[jj] = rloc * 8;                // wave-uniform LDS base (v8h units)
    }

    // ---- fragment read offsets (v8h units); lo buddy = ^4
    const int cq = lane >> 4;
    const int wr = wid >> 1, wc = wid & 1;
    int aOff[4], bOff[4];
    #pragma unroll
    for (int i = 0; i < 4; i++) {
        int am  = wr * 64 + i * 16 + (lane & 15);
        aOff[i] = am * 8 + (cq ^ (am & 7));
        int bn2 = wc * 64 + i * 16 + (lane & 15);
        bOff[i] = bn2 * 8 + (cq ^ (bn2 & 7));
    }

    v4f acc[4][4]  = {};
    v4f accx[4][4] = {};

    auto stage = [&](int buf, int k0) {
        v8h* Ab = As + buf * 1024;
        v8h* Bb = Bs + buf * 1024;
        #pragma unroll
        for (int jj = 0; jj < 4; jj++) gload_lds16(aS[jj] + k0, Ab + dOf[jj]);
        #pragma unroll
        for (int jj = 0; jj < 4; jj++) gload_lds16(bS[jj] + k0, Bb + dOf[jj]);
    };

    const int nsteps = K >> 5;
    stage(0, 0);
    __syncthreads();                       // compiler drains vmcnt before barrier

    for (int t = 0; t < nsteps; ++t) {
        const int cur = t & 1;
        if (t + 1 < nsteps) stage(cur ^ 1, (t + 1) * 32);

        const v8h* Ab = As + cur * 1024;
        const v8h* Bb = Bs + cur * 1024;
        v8h ah[4], al[4], bh[4], bl[4];
        #pragma unroll
        for (int i = 0; i < 4; i++) {
            ah[i] = Ab[aOff[i]]; al[i] = Ab[aOff[i] ^ 4];
            bh[i] = Bb[bOff[i]]; bl[i] = Bb[bOff[i] ^ 4];
        }
        #pragma unroll
        for (int mi = 0; mi < 4; mi++)
            #pragma unroll
            for (int ni = 0; ni < 4; ni++) {
                acc[mi][ni]  = __builtin_amdgcn_mfma_f32_16x16x32_f16(ah[mi], bh[ni], acc[mi][ni],  0, 0, 0);
                accx[mi][ni] = __builtin_amdgcn_mfma_f32_16x16x32_f16(ah[mi], bl[ni], accx[mi][ni], 0, 0, 0);
                accx[mi][ni] = __builtin_amdgcn_mfma_f32_16x16x32_f16(al[mi], bh[ni], accx[mi][ni], 0, 0, 0);
            }
        __syncthreads();                   // vmcnt(0)+barrier: next buf ready
    }

    // ---- epilogue
    const int rbase = (lane >> 4) * 4;
    const int cl    = lane & 15;
    #pragma unroll
    for (int ni = 0; ni < 4; ni++) {
        long col = bn + wc * 64 + ni * 16 + cl;
        float bv = 0.0f;
        if constexpr (HASBIAS) bv = bias[col];
        #pragma unroll
        for (int mi = 0; mi < 4; mi++) {
            #pragma unroll
            for (int r = 0; r < 4; r++) {
                long row = bm + wr * 64 + mi * 16 + rbase + r;
                float v = acc[mi][ni][r] + accx[mi][ni][r] * (1.0f / 2048.0f) + bv;
                if constexpr (RELU) v = fmaxf(v, 0.0f);
                if constexpr (WF32) C[row * (long)N + col] = v;
                if constexpr (WSPLIT) {
                    F16 h, l; split2(v, h, l);
                    Ch[row * (long)N + col] = h;
                    Cl[row * (long)N + col] = l;
                }
            }
        }
    }
}

// W: K x N fp32 -> H/L: N x K f16 split (transpose + split).
__global__ void wprep_kernel(const float* __restrict__ W, F16* __restrict__ H,
                             F16* __restrict__ L, int K, int N)
{
    int i = blockIdx.x * 256 + threadIdx.x;
    if (i >= K * N) return;
    int k = i / N, n = i % N;
    float v = W[i];
    F16 h, l; split2(v, h, l);
    H[(long)n * K + k] = h;
    L[(long)n * K + k] = l;
}

// codebooks already [level][n][k]-major: elementwise split.
__global__ void cbprep_kernel(const float* __restrict__ Cb, F16* __restrict__ H,
                              F16* __restrict__ L)
{
    int i = blockIdx.x * 256 + threadIdx.x;
    float v = Cb[i];
    F16 h, l; split2(v, h, l);
    H[i] = h; L[i] = l;
}

// x fp32 -> split, same layout (M x K row-major), vectorized.
__global__ void xsplit_kernel(const float* __restrict__ X, F16* __restrict__ H,
                              F16* __restrict__ L, long n4)
{
    long stride = (long)gridDim.x * 256;
    for (long i = blockIdx.x * 256 + threadIdx.x; i < n4; i += stride) {
        float4 v = reinterpret_cast<const float4*>(X)[i];
        v4h h, l; F16 hh, ll;
        split2(v.x, hh, ll); h[0] = hh; l[0] = ll;
        split2(v.y, hh, ll); h[1] = hh; l[1] = ll;
        split2(v.z, hh, ll); h[2] = hh; l[2] = ll;
        split2(v.w, hh, ll); h[3] = hh; l[3] = ll;
        reinterpret_cast<v4h*>(H)[i] = h;
        reinterpret_cast<v4h*>(L)[i] = l;
    }
}

// Per-row argmin over 256 codes + residual/x_q update + SSE accumulation.
// One wave per row; lane l owns codes {l, l+64, l+128, l+192} (first-index
// tie-break like jnp.argmin). Exact fp32 bookkeeping; also emits f16 splits
// for the next level's GEMM (or x_q's split at the last level).
__global__ __launch_bounds__(256)
void rq_update_kernel(const float* __restrict__ scores,  // [M][256] = r.C_j
                      const float* __restrict__ cb,      // [256][128] fp32
                      const float* __restrict__ src,     // z (level 0) or resid
                      float* __restrict__ resid,
                      F16* __restrict__ residh, F16* __restrict__ residl,
                      float* __restrict__ xq,
                      F16* __restrict__ xqh, F16* __restrict__ xql,
                      float* __restrict__ lossF,
                      int M, int first, int last)
{
    __shared__ float c2s[256];
    __shared__ float lsum[4];
    const int tid  = threadIdx.x;
    const int lane = tid & 63;
    const int wave = tid >> 6;

    {   float s = 0.f;
        #pragma unroll
        for (int d = 0; d < 128; d += 4) {
            float4 v = *reinterpret_cast<const float4*>(cb + (long)tid * 128 + d);
            s += v.x * v.x + v.y * v.y + v.z * v.z + v.w * v.w;
        }
        c2s[tid] = s;
    }
    __syncthreads();

    float myloss = 0.f;
    const int stride = gridDim.x * 4;
    for (int row = blockIdx.x * 4 + wave; row < M; row += stride) {
        const float* srow = scores + (long)row * 256;
        float best = 3.4e38f; int bidx = 0;
        #pragma unroll
        for (int j = 0; j < 4; j++) {
            int code = lane + j * 64;
            float d = fmaf(-2.f, srow[code], c2s[code]);
            if (d < best) { best = d; bidx = code; }
        }
        #pragma unroll
        for (int off = 32; off > 0; off >>= 1) {
            float ob = __shfl_down(best, off);
            int   oi = __shfl_down(bidx, off);
            if (ob < best || (ob == best && oi < bidx)) { best = ob; bidx = oi; }
        }
        bidx = __shfl(bidx, 0);

        long base = (long)row * 128 + lane * 2;
        float2 r = *reinterpret_cast<const float2*>(src + base);
        float2 q = *reinterpret_cast<const float2*>(cb + (long)bidx * 128 + lane * 2);
        float dx = r.x - q.x, dy = r.y - q.y;
        myloss += dx * dx + dy * dy;

        if (!last) {
            float2 nr; nr.x = dx; nr.y = dy;
            *reinterpret_cast<float2*>(resid + base) = nr;
            v2h nh, nl; F16 h, l;
            split2(dx, h, l); nh[0] = h; nl[0] = l;
            split2(dy, h, l); nh[1] = h; nl[1] = l;
            *reinterpret_cast<v2h*>(residh + base) = nh;
            *reinterpret_cast<v2h*>(residl + base) = nl;
        }
        float2 xv;
        if (first) { xv.x = q.x; xv.y = q.y; }
        else {
            xv = *reinterpret_cast<float2*>(xq + base);
            xv.x += q.x; xv.y += q.y;
        }
        if (!last) {
            *reinterpret_cast<float2*>(xq + base) = xv;
        } else {
            v2h nh, nl; F16 h, l;
            split2(xv.x, h, l); nh[0] = h; nl[0] = l;
            split2(xv.y, h, l); nh[1] = h; nl[1] = l;
            *reinterpret_cast<v2h*>(xqh + base) = nh;
            *reinterpret_cast<v2h*>(xql + base) = nl;
        }
    }

    #pragma unroll
    for (int off = 32; off > 0; off >>= 1) myloss += __shfl_down(myloss, off);
    if (lane == 0) lsum[wave] = myloss;
    __syncthreads();
    if (tid == 0) atomicAdd(lossF, (lsum[0] + lsum[1]) + (lsum[2] + lsum[3]));
}

__global__ void zero4_kernel(float* __restrict__ F)
{
    if (threadIdx.x < 4) F[threadIdx.x] = 0.f;
}

__global__ void finalize_loss_kernel(const float* __restrict__ F, float* __restrict__ out)
{
    if (threadIdx.x == 0) {
        float s = (F[0] + F[1]) + (F[2] + F[3]);
        out[0] = s * (1.25f / (4.f * 65536.f * 128.f));
    }
}

extern "C" void kernel_launch(void* const* d_in, const int* in_sizes, int n_in,
                              void* d_out, int out_size, void* d_ws, size_t ws_size,
                              hipStream_t stream)
{
    const float* x      = (const float*)d_in[0];
    const float* enc_w0 = (const float*)d_in[1];
    const float* enc_b0 = (const float*)d_in[2];
    const float* enc_w1 = (const float*)d_in[3];
    const float* enc_b1 = (const float*)d_in[4];
    const float* enc_w2 = (const float*)d_in[5];
    const float* enc_b2 = (const float*)d_in[6];
    const float* dec_w0 = (const float*)d_in[7];
    const float* dec_b0 = (const float*)d_in[8];
    const float* dec_w1 = (const float*)d_in[9];
    const float* dec_b1 = (const float*)d_in[10];
    const float* dec_w2 = (const float*)d_in[11];
    const float* dec_b2 = (const float*)d_in[12];
    const float* codebooks = (const float*)d_in[13];

    const int M = 65536;

    // ---------------- memory overlay (all offsets in f16 / float units) ----
    // ws (201.3 MB = 100,663,296 f16):
    //   [0, 100.66M f16): Xh+Xl (dead after enc0), then:
    //     z   fp32 @ f32[0,       8.39M)   } resid in-place
    //     zh  f16  @ f16[16.78M, 25.17M)   } resids in-place
    //     zl  f16  @ f16[25.17M, 33.55M)
    //     g2l f16  @ f16[0,      33.55M)   (after z/zs dead)
    //     g2h f16  @ f16[33.55M, 67.11M)
    //   [67.11M, 100.66M f16): h2s -> scores(f32) -> g1s -> d2s
    F16*   wsF = (F16*)d_ws;
    float* wsf = (float*)d_ws;
    F16*   Xh  = wsF;                         // 50,331,648
    F16*   Xl  = wsF + 50331648;
    float* z   = wsf;                         // 8,388,608 floats
    F16*   zh  = wsF + 16777216;              // 8,388,608
    F16*   zl  = wsF + 25165824;
    F16*   g2l = wsF;                         // 33,554,432
    F16*   g2h = wsF + 33554432;              // 33,554,432
    F16*   h2h = wsF + 67108864;              // 16,777,216
    F16*   h2l = wsF + 83886080;
    float* scores = wsf + 33554432;           // 16,777,216 floats
    F16*   g1h = wsF + 67108864;              // 16,777,216
    F16*   g1l = wsF + 83886080;
    F16*   d2h = wsF + 67108864;              // 393,216 (prepped after dec1)
    F16*   d2l = d2h + 393216;

    // d_out (201.3 MB + 4 B):
    //   h1s f16 @ [0, 67.11M f16) x2 (dead after enc1), then:
    //     xq  fp32 @ f32[0, 8.39M) ; xqh/xql @ f16[16.78M, 33.55M)
    //   weight splits + F @ f16[67.11M, ...) (dead before dec2 writes y)
    //   y fp32 @ [0, 50,331,648); loss @ f32[50,331,648]
    F16*   doF = (F16*)d_out;
    float* y   = (float*)d_out;
    F16*   h1h = doF;                         // 33,554,432
    F16*   h1l = doF + 33554432;
    float* xq  = (float*)d_out;               // 8,388,608 floats
    F16*   xqh = doF + 16777216;              // 8,388,608
    F16*   xql = doF + 25165824;
    F16*   w_  = doF + 67108864;              // weight-split arena (~3.4 MB)
    F16* e0h = w_;              F16* e0l = e0h + 393216;
    F16* e1h = e0l + 393216;    F16* e1l = e1h + 131072;
    F16* e2h = e1l + 131072;    F16* e2l = e2h + 32768;
    F16* d0h = e2l + 32768;     F16* d0l = d0h + 32768;
    F16* d1h = d0l + 32768;     F16* d1l = d1h + 131072;
    F16* cbh = d1l + 131072;    F16* cbl = cbh + 131072;
    float* F = (float*)d_out + 35000000;      // loss accum (consumed pre-decoder)

    dim3 blk(256);

    // ---- prep ----
    wprep_kernel<<<dim3(1536), blk, 0, stream>>>(enc_w0, e0h, e0l, 768, 512);
    wprep_kernel<<<dim3(512),  blk, 0, stream>>>(enc_w1, e1h, e1l, 512, 256);
    wprep_kernel<<<dim3(128),  blk, 0, stream>>>(enc_w2, e2h, e2l, 256, 128);
    wprep_kernel<<<dim3(128),  blk, 0, stream>>>(dec_w0, d0h, d0l, 128, 256);
    wprep_kernel<<<dim3(512),  blk, 0, stream>>>(dec_w1, d1h, d1l, 256, 512);
    cbprep_kernel<<<dim3(512), blk, 0, stream>>>(codebooks, cbh, cbl);
    xsplit_kernel<<<dim3(4096), blk, 0, stream>>>(x, Xh, Xl, 12582912);
    zero4_kernel<<<dim3(1), dim3(64), 0, stream>>>(F);

    // ---- encoder ----
    f16gemm2<true,  true, false, true ><<<dim3(2048), blk, 0, stream>>>(Xh, Xl, e0h, e0l, enc_b0, nullptr, h1h, h1l, 512, 768, 4);
    f16gemm2<true,  true, false, true ><<<dim3(1024), blk, 0, stream>>>(h1h, h1l, e1h, e1l, enc_b1, nullptr, h2h, h2l, 256, 512, 2);
    f16gemm2<false, true, true,  true ><<<dim3(512),  blk, 0, stream>>>(h2h, h2l, e2h, e2l, enc_b2, z, zh, zl, 128, 256, 1);

    // ---- residual quantization (4 levels) ----
    for (int l = 0; l < 4; l++) {
        const float* cb = codebooks + (long)l * 32768;
        const float* src = (l == 0) ? z : z;   // resid lives in z buffer (in-place)
        f16gemm2<false, false, true, false><<<dim3(1024), blk, 0, stream>>>(zh, zl, cbh + l * 32768, cbl + l * 32768,
                                                                            nullptr, scores, nullptr, nullptr, 256, 128, 2);
        rq_update_kernel<<<dim3(1024), blk, 0, stream>>>(scores, cb, src, z, zh, zl, xq, xqh, xql,
                                                         F + l, M, (l == 0) ? 1 : 0, (l == 3) ? 1 : 0);
    }
    finalize_loss_kernel<<<dim3(1), dim3(64), 0, stream>>>(F, y + 50331648);

    // ---- decoder (y_q == x_q numerically) ----
    f16gemm2<true,  true, false, true ><<<dim3(1024), blk, 0, stream>>>(xqh, xql, d0h, d0l, dec_b0, nullptr, g1h, g1l, 256, 128, 2);
    f16gemm2<true,  true, false, true ><<<dim3(2048), blk, 0, stream>>>(g1h, g1l, d1h, d1l, dec_b1, nullptr, g2h, g2l, 512, 256, 4);
    wprep_kernel<<<dim3(1536), blk, 0, stream>>>(dec_w2, d2h, d2l, 512, 768);
    f16gemm2<false, true, true,  false><<<dim3(3072), blk, 0, stream>>>(g2h, g2l, d2h, d2l, dec_b2, y, nullptr, nullptr, 768, 512, 6);
}

// Round 4
// 1146.949 us; speedup vs baseline: 1.1433x; 1.1433x over previous
//
#include <hip/hip_runtime.h>
#include <cstdint>
#include <cstddef>

// ---------------------------------------------------------------------------
// RQ-VAE forward. MFMA GEMMs via 2-term f16 split (hi + lo*2048): chains
// hh / h*lo / lo*h, cross-accumulator scaled 1/2048 at epilogue (lo stays in
// normal f16 range -> no denorm hazard). ~2^-22 relative precision.
// K-loop: double-buffered LDS, counted s_waitcnt vmcnt(8) (loads stay in
// flight across barriers), 2 raw barriers/iter, setprio around MFMA cluster.
// Epilogue: LDS-transpose for coalesced float4/v4h stores; RQ score GEMM
// fuses the per-row argmin (no score matrix materialized).
// RQ bookkeeping (argmin pick, residual, loss) stays exact fp32.
// ---------------------------------------------------------------------------

typedef _Float16 F16;
typedef F16   v8h  __attribute__((ext_vector_type(8)));
typedef F16   v2h  __attribute__((ext_vector_type(2)));
typedef F16   v4h  __attribute__((ext_vector_type(4)));
typedef float v4f  __attribute__((ext_vector_type(4)));

__device__ __forceinline__ void gload_lds16(const void* g, void* l) {
    __builtin_amdgcn_global_load_lds(
        (const __attribute__((address_space(1))) void*)g,
        (__attribute__((address_space(3))) void*)l, 16, 0, 0);
}

__device__ __forceinline__ void split2(float v, F16& h, F16& l) {
    h = (F16)v;
    l = (F16)((v - (float)h) * 2048.0f);
}

// ---------------------------------------------------------------------------
// OUT: 0 = fp32 C, 1 = split C (Ch/Cl), 2 = both, 3 = argmin candidates.
// A: M x K split row-major. B: N x K split row-major. Tile 128x128, BK=32,
// 4 waves (2x2), 64x64/wave, 3 chains of mfma_f32_16x16x32_f16.
// LDS per row: 8 x 16B chunks, phys = logical ^ (row&7); 0-3 hi, 4-7 lo.
// Grid 1-D, XCD-bijective swizzle (gridDim %8==0), N-inner.
// ---------------------------------------------------------------------------
template<int OUT, bool RELU, bool HASBIAS>
__global__ __launch_bounds__(256, 2)
void f16gemm3(const F16* __restrict__ Ah, const F16* __restrict__ Al,
              const F16* __restrict__ Bh, const F16* __restrict__ Bl,
              const float* __restrict__ bias,
              float* __restrict__ C, F16* __restrict__ Ch, F16* __restrict__ Cl,
              const float* __restrict__ c2, float2* __restrict__ cand,
              int N, int K, int nbn)
{
    __shared__ __attribute__((aligned(16))) char smem[67584];
    v8h* As = (v8h*)smem;              // [2][1024] 32 KB
    v8h* Bs = (v8h*)(smem + 32768);    // [2][1024] 32 KB

    const int tid  = threadIdx.x;
    const int lane = tid & 63;
    const int wid  = tid >> 6;

    const int cpx = gridDim.x >> 3;
    const int sw  = (blockIdx.x & 7) * cpx + (blockIdx.x >> 3);
    const int mt  = sw / nbn;
    const int nt_ = sw - mt * nbn;
    const long bm = (long)mt * 128;
    const long bn = (long)nt_ * 128;

    // staging: wave w rows [32w,32w+32), 4 gload_lds per operand
    const int rr = lane >> 3;
    const int c  = (lane & 7) ^ rr;
    const F16* aS[4]; const F16* bS[4];
    int dOf[4];
    #pragma unroll
    for (int jj = 0; jj < 4; jj++) {
        int rloc = wid * 32 + jj * 8;
        long ag = bm + rloc + rr, bg = bn + rloc + rr;
        aS[jj] = (c < 4) ? (Ah + ag * (long)K + c * 8) : (Al + ag * (long)K + (c - 4) * 8);
        bS[jj] = (c < 4) ? (Bh + bg * (long)K + c * 8) : (Bl + bg * (long)K + (c - 4) * 8);
        dOf[jj] = rloc * 8;
    }

    const int cq = lane >> 4;
    const int wr = wid >> 1, wc = wid & 1;
    int aOff[4], bOff[4];
    #pragma unroll
    for (int i = 0; i < 4; i++) {
        int am  = wr * 64 + i * 16 + (lane & 15);
        aOff[i] = am * 8 + (cq ^ (am & 7));
        int bn2 = wc * 64 + i * 16 + (lane & 15);
        bOff[i] = bn2 * 8 + (cq ^ (bn2 & 7));
    }

    v4f acc[4][4]  = {};
    v4f accx[4][4] = {};

    auto stage = [&](int buf, int k0) {
        v8h* Ab = As + buf * 1024;
        v8h* Bb = Bs + buf * 1024;
        #pragma unroll
        for (int jj = 0; jj < 4; jj++) gload_lds16(aS[jj] + k0, Ab + dOf[jj]);
        #pragma unroll
        for (int jj = 0; jj < 4; jj++) gload_lds16(bS[jj] + k0, Bb + dOf[jj]);
    };

    const int nsteps = K >> 5;
    stage(0, 0);

    for (int t = 0; t < nsteps; ++t) {
        const int cur = t & 1;
        if (t + 1 < nsteps) {
            stage(cur ^ 1, (t + 1) * 32);
            asm volatile("s_waitcnt vmcnt(8)" ::: "memory");  // prev tile landed
        } else {
            asm volatile("s_waitcnt vmcnt(0)" ::: "memory");
        }
        __builtin_amdgcn_sched_barrier(0);
        __builtin_amdgcn_s_barrier();                          // all waves' data in
        __builtin_amdgcn_sched_barrier(0);

        const v8h* Ab = As + cur * 1024;
        const v8h* Bb = Bs + cur * 1024;
        v8h ah[4], al[4], bh[4], bl[4];
        #pragma unroll
        for (int i = 0; i < 4; i++) {
            ah[i] = Ab[aOff[i]]; al[i] = Ab[aOff[i] ^ 4];
            bh[i] = Bb[bOff[i]]; bl[i] = Bb[bOff[i] ^ 4];
        }
        __builtin_amdgcn_s_setprio(1);
        #pragma unroll
        for (int mi = 0; mi < 4; mi++)
            #pragma unroll
            for (int ni = 0; ni < 4; ni++) {
                acc[mi][ni]  = __builtin_amdgcn_mfma_f32_16x16x32_f16(ah[mi], bh[ni], acc[mi][ni],  0, 0, 0);
                accx[mi][ni] = __builtin_amdgcn_mfma_f32_16x16x32_f16(ah[mi], bl[ni], accx[mi][ni], 0, 0, 0);
                accx[mi][ni] = __builtin_amdgcn_mfma_f32_16x16x32_f16(al[mi], bh[ni], accx[mi][ni], 0, 0, 0);
            }
        __builtin_amdgcn_s_setprio(0);
        __builtin_amdgcn_sched_barrier(0);
        __builtin_amdgcn_s_barrier();                          // release buf[cur]
        __builtin_amdgcn_sched_barrier(0);
    }

    const int cl = lane & 15;
    const int rb = (lane >> 4) * 4;

    if constexpr (OUT == 3) {
        // ---- fused argmin epilogue: dist = c2[code] - 2*s ----
        float* cD = (float*)smem;
        int*   cI = (int*)(smem + 1024);
        float bd[4][4]; int bi[4][4];
        #pragma unroll
        for (int mi = 0; mi < 4; mi++)
            #pragma unroll
            for (int r = 0; r < 4; r++) {
                float bb = 3.4e38f; int ii = 0;
                #pragma unroll
                for (int ni = 0; ni < 4; ni++) {
                    int code = (int)bn + wc * 64 + ni * 16 + cl;
                    float s  = acc[mi][ni][r] + accx[mi][ni][r] * (1.0f / 2048.0f);
                    float d  = fmaf(-2.0f, s, c2[code]);
                    if (d < bb || (d == bb && code < ii)) { bb = d; ii = code; }
                }
                bd[mi][r] = bb; bi[mi][r] = ii;
            }
        #pragma unroll
        for (int off = 1; off < 16; off <<= 1)
            #pragma unroll
            for (int mi = 0; mi < 4; mi++)
                #pragma unroll
                for (int r = 0; r < 4; r++) {
                    float od = __shfl_xor(bd[mi][r], off);
                    int   oi = __shfl_xor(bi[mi][r], off);
                    if (od < bd[mi][r] || (od == bd[mi][r] && oi < bi[mi][r])) {
                        bd[mi][r] = od; bi[mi][r] = oi;
                    }
                }
        if (cl == 0)
            #pragma unroll
            for (int mi = 0; mi < 4; mi++)
                #pragma unroll
                for (int r = 0; r < 4; r++) {
                    int rl = wr * 64 + mi * 16 + rb + r;
                    cD[rl * 2 + wc] = bd[mi][r];
                    cI[rl * 2 + wc] = bi[mi][r];
                }
        __syncthreads();
        if (tid < 128) {
            float d0 = cD[tid * 2], d1 = cD[tid * 2 + 1];
            int   i0 = cI[tid * 2], i1 = cI[tid * 2 + 1];
            float pd; int pk;
            if (d1 < d0 || (d1 == d0 && i1 < i0)) { pd = d1; pk = i1; }
            else                                  { pd = d0; pk = i0; }
            float2 out; out.x = pd; out.y = __int_as_float(pk);
            cand[(bm + tid) * 2 + (bn >> 7)] = out;
        }
    } else {
        // ---- LDS-transpose epilogue: coalesced wide stores ----
        float* sC = (float*)smem;    // stride 132
        #pragma unroll
        for (int mi = 0; mi < 4; mi++)
            #pragma unroll
            for (int ni = 0; ni < 4; ni++)
                #pragma unroll
                for (int r = 0; r < 4; r++)
                    sC[(wr * 64 + mi * 16 + rb + r) * 132 + wc * 64 + ni * 16 + cl] =
                        acc[mi][ni][r] + accx[mi][ni][r] * (1.0f / 2048.0f);
        __syncthreads();
        const int trow = tid >> 5;
        const int tcol = (tid & 31) << 2;
        float4 bv = {0.f, 0.f, 0.f, 0.f};
        if constexpr (HASBIAS) bv = *reinterpret_cast<const float4*>(bias + bn + tcol);
        #pragma unroll
        for (int it = 0; it < 16; ++it) {
            int row = trow + it * 8;
            float4 v = *reinterpret_cast<const float4*>(&sC[row * 132 + tcol]);
            v.x += bv.x; v.y += bv.y; v.z += bv.z; v.w += bv.w;
            if constexpr (RELU) {
                v.x = fmaxf(v.x, 0.f); v.y = fmaxf(v.y, 0.f);
                v.z = fmaxf(v.z, 0.f); v.w = fmaxf(v.w, 0.f);
            }
            long gr = (bm + row) * (long)N + bn + tcol;
            if constexpr (OUT == 0 || OUT == 2)
                *reinterpret_cast<float4*>(C + gr) = v;
            if constexpr (OUT == 1 || OUT == 2) {
                v4h h4, l4; F16 h, l;
                split2(v.x, h, l); h4[0] = h; l4[0] = l;
                split2(v.y, h, l); h4[1] = h; l4[1] = l;
                split2(v.z, h, l); h4[2] = h; l4[2] = l;
                split2(v.w, h, l); h4[3] = h; l4[3] = l;
                *reinterpret_cast<v4h*>(Ch + gr) = h4;
                *reinterpret_cast<v4h*>(Cl + gr) = l4;
            }
        }
    }
}

// W: K x N fp32 -> H/L: N x K f16 split (transpose + split).
__device__ __forceinline__ void wprep_task(const float* __restrict__ W,
                                           F16* __restrict__ H, F16* __restrict__ L,
                                           int K, int N, int idx, int stride, int total)
{
    for (int i = idx; i < total; i += stride) {
        int k = i / N, n = i - k * N;
        float v = W[i];
        F16 h, l; split2(v, h, l);
        H[(long)n * K + k] = h;
        L[(long)n * K + k] = l;
    }
}

// All launch-time prep in ONE dispatch: x split, 5 weight splits, codebook
// split, c2 table (exact float4 chain), loss-accumulator zero.
__global__ __launch_bounds__(256)
void prep_all(const float* __restrict__ x,
              const float* __restrict__ ew0, const float* __restrict__ ew1,
              const float* __restrict__ ew2, const float* __restrict__ dw0,
              const float* __restrict__ dw1, const float* __restrict__ cball,
              F16* __restrict__ Xh, F16* __restrict__ Xl,
              F16* __restrict__ e0h, F16* __restrict__ e0l,
              F16* __restrict__ e1h, F16* __restrict__ e1l,
              F16* __restrict__ e2h, F16* __restrict__ e2l,
              F16* __restrict__ d0h, F16* __restrict__ d0l,
              F16* __restrict__ d1h, F16* __restrict__ d1l,
              F16* __restrict__ cbh, F16* __restrict__ cbl,
              float* __restrict__ c2all, float* __restrict__ F)
{
    const int b = blockIdx.x, t = threadIdx.x;
    if (b < 3072) {
        for (long i = (long)b * 256 + t; i < 12582912; i += 786432) {
            float4 v = reinterpret_cast<const float4*>(x)[i];
            v4h h4, l4; F16 h, l;
            split2(v.x, h, l); h4[0] = h; l4[0] = l;
            split2(v.y, h, l); h4[1] = h; l4[1] = l;
            split2(v.z, h, l); h4[2] = h; l4[2] = l;
            split2(v.w, h, l); h4[3] = h; l4[3] = l;
            reinterpret_cast<v4h*>(Xh)[i] = h4;
            reinterpret_cast<v4h*>(Xl)[i] = l4;
        }
    } else if (b < 3584) wprep_task(ew0, e0h, e0l, 768, 512, (b - 3072) * 256 + t, 131072, 393216);
    else if (b < 3712)   wprep_task(ew1, e1h, e1l, 512, 256, (b - 3584) * 256 + t, 32768, 131072);
    else if (b < 3744)   wprep_task(ew2, e2h, e2l, 256, 128, (b - 3712) * 256 + t, 8192, 32768);
    else if (b < 3776)   wprep_task(dw0, d0h, d0l, 128, 256, (b - 3744) * 256 + t, 8192, 32768);
    else if (b < 3904)   wprep_task(dw1, d1h, d1l, 256, 512, (b - 3776) * 256 + t, 32768, 131072);
    else if (b < 4032) {
        for (int i = (b - 3904) * 256 + t; i < 131072; i += 32768) {
            float v = cball[i];
            F16 h, l; split2(v, h, l);
            cbh[i] = h; cbl[i] = l;
        }
    } else if (b < 4036) {
        int i = (b - 4032) * 256 + t;      // 0..1023 = level*256 + code
        const float* row = cball + (long)i * 128;
        float s = 0.f;
        #pragma unroll
        for (int d = 0; d < 128; d += 4) {
            float4 v = *reinterpret_cast<const float4*>(row + d);
            s += v.x * v.x + v.y * v.y + v.z * v.z + v.w * v.w;
        }
        c2all[i] = s;
    } else {
        if (t < 4) F[t] = 0.f;
    }
}

// standalone wprep for dec_w2 (must run after dec1 frees its ws region)
__global__ void wprep_kernel(const float* __restrict__ W, F16* __restrict__ H,
                             F16* __restrict__ L, int K, int N)
{
    int i = blockIdx.x * 256 + threadIdx.x;
    if (i >= K * N) return;
    wprep_task(W, H, L, K, N, i, K * N, i + 1);
}

// Per-row: pick winner from 2 candidate halves (tiebreak lower idx, matching
// jnp.argmin), then exact fp32 residual/x_q/loss update + f16 splits.
__global__ __launch_bounds__(256)
void rq_update2(const float2* __restrict__ cand,
                const float* __restrict__ cb,      // this level, fp32 [256][128]
                const float* __restrict__ src,
                float* __restrict__ resid,
                F16* __restrict__ residh, F16* __restrict__ residl,
                float* __restrict__ xq,
                F16* __restrict__ xqh, F16* __restrict__ xql,
                float* __restrict__ lossF,
                int M, int first, int last)
{
    __shared__ float lsum[4];
    const int tid  = threadIdx.x;
    const int lane = tid & 63;
    const int wave = tid >> 6;

    float myloss = 0.f;
    const int stride = gridDim.x * 4;
    for (int row = blockIdx.x * 4 + wave; row < M; row += stride) {
        float2 c0 = cand[(long)row * 2];
        float2 c1 = cand[(long)row * 2 + 1];
        int i0 = __float_as_int(c0.y), i1 = __float_as_int(c1.y);
        int bidx = (c1.x < c0.x || (c1.x == c0.x && i1 < i0)) ? i1 : i0;

        long base = (long)row * 128 + lane * 2;
        float2 r = *reinterpret_cast<const float2*>(src + base);
        float2 q = *reinterpret_cast<const float2*>(cb + (long)bidx * 128 + lane * 2);
        float dx = r.x - q.x, dy = r.y - q.y;
        myloss += dx * dx + dy * dy;

        if (!last) {
            float2 nr; nr.x = dx; nr.y = dy;
            *reinterpret_cast<float2*>(resid + base) = nr;
            v2h nh, nl; F16 h, l;
            split2(dx, h, l); nh[0] = h; nl[0] = l;
            split2(dy, h, l); nh[1] = h; nl[1] = l;
            *reinterpret_cast<v2h*>(residh + base) = nh;
            *reinterpret_cast<v2h*>(residl + base) = nl;
        }
        float2 xv;
        if (first) { xv.x = q.x; xv.y = q.y; }
        else {
            xv = *reinterpret_cast<float2*>(xq + base);
            xv.x += q.x; xv.y += q.y;
        }
        if (!last) {
            *reinterpret_cast<float2*>(xq + base) = xv;
        } else {
            v2h nh, nl; F16 h, l;
            split2(xv.x, h, l); nh[0] = h; nl[0] = l;
            split2(xv.y, h, l); nh[1] = h; nl[1] = l;
            *reinterpret_cast<v2h*>(xqh + base) = nh;
            *reinterpret_cast<v2h*>(xql + base) = nl;
        }
    }

    #pragma unroll
    for (int off = 32; off > 0; off >>= 1) myloss += __shfl_down(myloss, off);
    if (lane == 0) lsum[wave] = myloss;
    __syncthreads();
    if (tid == 0) atomicAdd(lossF, (lsum[0] + lsum[1]) + (lsum[2] + lsum[3]));
}

__global__ void finalize_loss_kernel(const float* __restrict__ F, float* __restrict__ out)
{
    if (threadIdx.x == 0) {
        float s = (F[0] + F[1]) + (F[2] + F[3]);
        out[0] = s * (1.25f / (4.f * 65536.f * 128.f));
    }
}

extern "C" void kernel_launch(void* const* d_in, const int* in_sizes, int n_in,
                              void* d_out, int out_size, void* d_ws, size_t ws_size,
                              hipStream_t stream)
{
    const float* x      = (const float*)d_in[0];
    const float* enc_w0 = (const float*)d_in[1];
    const float* enc_b0 = (const float*)d_in[2];
    const float* enc_w1 = (const float*)d_in[3];
    const float* enc_b1 = (const float*)d_in[4];
    const float* enc_w2 = (const float*)d_in[5];
    const float* enc_b2 = (const float*)d_in[6];
    const float* dec_w0 = (const float*)d_in[7];
    const float* dec_b0 = (const float*)d_in[8];
    const float* dec_w1 = (const float*)d_in[9];
    const float* dec_b1 = (const float*)d_in[10];
    const float* dec_w2 = (const float*)d_in[11];
    const float* dec_b2 = (const float*)d_in[12];
    const float* codebooks = (const float*)d_in[13];

    const int M = 65536;

    // ws overlay (201.3 MB = 100,663,296 f16):
    //   Xh [0,50.3M) Xl [50.3M,100.7M)        (dead after enc0)
    //   z f32[0,8.4M)  zh f16[16.8M,25.2M)  zl [25.2M,33.5M)   (rq, in-place)
    //   g2l [0,33.5M)  g2h [33.5M,67.1M)       (dec1 out)
    //   h2h [67.1M,83.9M) h2l [83.9M,100.7M) -> g1h/g1l -> d2h/d2l
    F16*   wsF = (F16*)d_ws;
    float* wsf = (float*)d_ws;
    F16*   Xh  = wsF;
    F16*   Xl  = wsF + 50331648;
    float* z   = wsf;
    F16*   zh  = wsF + 16777216;
    F16*   zl  = wsF + 25165824;
    F16*   g2l = wsF;
    F16*   g2h = wsF + 33554432;
    F16*   h2h = wsF + 67108864;
    F16*   h2l = wsF + 83886080;
    F16*   g1h = wsF + 67108864;
    F16*   g1l = wsF + 83886080;
    F16*   d2h = wsF + 67108864;
    F16*   d2l = d2h + 393216;

    // d_out overlay:
    //   h1h f16[0,33.5M) h1l [33.5M,67.1M)     (dead after enc1)
    //   xq f32[0,8.4M) ; xqh f16[16.8M,25.2M) xql [25.2M,33.5M)
    //   arena @ f16 67,108,864: weight splits | cand | c2all | F  (dead pre-dec2)
    //   y f32[0,50331648) + loss @ [50331648]
    F16*   doF = (F16*)d_out;
    float* y   = (float*)d_out;
    F16*   h1h = doF;
    F16*   h1l = doF + 33554432;
    float* xq  = (float*)d_out;
    F16*   xqh = doF + 16777216;
    F16*   xql = doF + 25165824;
    F16* e0h = doF + 67108864;  F16* e0l = e0h + 393216;
    F16* e1h = e0l + 393216;    F16* e1l = e1h + 131072;
    F16* e2h = e1l + 131072;    F16* e2l = e2h + 32768;
    F16* d0h = e2l + 32768;     F16* d0l = d0h + 32768;
    F16* d1h = d0l + 32768;     F16* d1l = d1h + 131072;
    F16* cbh = d1l + 131072;    F16* cbl = cbh + 131072;
    float2* cand  = (float2*)(doF + 68812800);            // 65536 x 2
    float*  c2all = (float*)(doF + 69337088);             // 1024
    float*  F     = c2all + 1024;

    dim3 blk(256);

    prep_all<<<dim3(4037), blk, 0, stream>>>(x, enc_w0, enc_w1, enc_w2, dec_w0, dec_w1,
                                             codebooks, Xh, Xl, e0h, e0l, e1h, e1l,
                                             e2h, e2l, d0h, d0l, d1h, d1l, cbh, cbl,
                                             c2all, F);

    // ---- encoder ----
    f16gemm3<1, true,  true><<<dim3(2048), blk, 0, stream>>>(Xh, Xl, e0h, e0l, enc_b0, nullptr, h1h, h1l, nullptr, nullptr, 512, 768, 4);
    f16gemm3<1, true,  true><<<dim3(1024), blk, 0, stream>>>(h1h, h1l, e1h, e1l, enc_b1, nullptr, h2h, h2l, nullptr, nullptr, 256, 512, 2);
    f16gemm3<2, false, true><<<dim3(512),  blk, 0, stream>>>(h2h, h2l, e2h, e2l, enc_b2, z, zh, zl, nullptr, nullptr, 128, 256, 1);

    // ---- residual quantization ----
    for (int l = 0; l < 4; l++) {
        const float* cb = codebooks + (long)l * 32768;
        f16gemm3<3, false, false><<<dim3(1024), blk, 0, stream>>>(zh, zl, cbh + l * 32768, cbl + l * 32768,
                                                                  nullptr, nullptr, nullptr, nullptr,
                                                                  c2all + l * 256, cand, 256, 128, 2);
        rq_update2<<<dim3(1024), blk, 0, stream>>>(cand, cb, z, z, zh, zl, xq, xqh, xql,
                                                   F + l, M, (l == 0) ? 1 : 0, (l == 3) ? 1 : 0);
    }
    finalize_loss_kernel<<<dim3(1), dim3(64), 0, stream>>>(F, y + 50331648);

    // ---- decoder ----
    f16gemm3<1, true,  true><<<dim3(1024), blk, 0, stream>>>(xqh, xql, d0h, d0l, dec_b0, nullptr, g1h, g1l, nullptr, nullptr, 256, 128, 2);
    f16gemm3<1, true,  true><<<dim3(2048), blk, 0, stream>>>(g1h, g1l, d1h, d1l, dec_b1, nullptr, g2h, g2l, nullptr, nullptr, 512, 256, 4);
    wprep_kernel<<<dim3(1536), blk, 0, stream>>>(dec_w2, d2h, d2l, 512, 768);
    f16gemm3<0, false, true><<<dim3(3072), blk, 0, stream>>>(g2h, g2l, d2h, d2l, dec_b2, y, nullptr, nullptr, nullptr, nullptr, 768, 512, 6);
}

// Round 5
// 1119.656 us; speedup vs baseline: 1.1712x; 1.0244x over previous
//
#include <hip/hip_runtime.h>
#include <cstdint>
#include <cstddef>

// ---------------------------------------------------------------------------
// RQ-VAE forward. MFMA GEMMs via 2-term f16 split (hi + lo*2048): chains
// hh / h*lo / lo*h, cross-accumulator scaled 1/2048 at epilogue (lo stays in
// normal f16 range -> no denorm hazard). ~2^-22 relative precision.
// K-loop: double-buffered LDS, counted s_waitcnt vmcnt(8), 2 raw barriers
// per step, and a phase-interleaved body: 3 ds_read phases feeding 4 MFMA
// quadrant-clusters (12 MFMA each) so reads complete >=1 cluster ahead
// (compiler emits counted lgkmcnt instead of a full drain).
// Residuals live as split-f16 only; x_q = z - resid_final at the last level.
// RQ bookkeeping (argmin pick, loss) matches jnp.argmin semantics.
// ---------------------------------------------------------------------------

typedef _Float16 F16;
typedef F16   v8h  __attribute__((ext_vector_type(8)));
typedef F16   v2h  __attribute__((ext_vector_type(2)));
typedef F16   v4h  __attribute__((ext_vector_type(4)));
typedef float v4f  __attribute__((ext_vector_type(4)));

__device__ __forceinline__ void gload_lds16(const void* g, void* l) {
    __builtin_amdgcn_global_load_lds(
        (const __attribute__((address_space(1))) void*)g,
        (__attribute__((address_space(3))) void*)l, 16, 0, 0);
}

__device__ __forceinline__ void split2(float v, F16& h, F16& l) {
    h = (F16)v;
    l = (F16)((v - (float)h) * 2048.0f);
}

#define MFMA3(mi, ni) \
    acc[mi][ni]  = __builtin_amdgcn_mfma_f32_16x16x32_f16(ah[mi], bh[ni], acc[mi][ni],  0, 0, 0); \
    accx[mi][ni] = __builtin_amdgcn_mfma_f32_16x16x32_f16(ah[mi], bl[ni], accx[mi][ni], 0, 0, 0); \
    accx[mi][ni] = __builtin_amdgcn_mfma_f32_16x16x32_f16(al[mi], bh[ni], accx[mi][ni], 0, 0, 0);

#define CLUSTER(ma, mb, na, nb) \
    __builtin_amdgcn_s_setprio(1); \
    MFMA3(ma, na) MFMA3(ma, nb) MFMA3(mb, na) MFMA3(mb, nb) \
    __builtin_amdgcn_s_setprio(0); \
    __builtin_amdgcn_sched_barrier(0);

// ---------------------------------------------------------------------------
// OUT: 0 = fp32 C, 1 = split C (Ch/Cl), 2 = both, 3 = argmin candidates.
// A: M x K split row-major. B: N x K split row-major. Tile 128x128, BK=32,
// 4 waves (2x2), 64x64/wave, 3 chains of mfma_f32_16x16x32_f16.
// LDS per row: 8 x 16B chunks, phys = logical ^ (row&7); 0-3 hi, 4-7 lo.
// Grid 1-D, XCD-bijective swizzle (gridDim %8==0), N-inner.
// ---------------------------------------------------------------------------
template<int OUT, bool RELU, bool HASBIAS>
__global__ __launch_bounds__(256, 2)
void f16gemm3(const F16* __restrict__ Ah, const F16* __restrict__ Al,
              const F16* __restrict__ Bh, const F16* __restrict__ Bl,
              const float* __restrict__ bias,
              float* __restrict__ C, F16* __restrict__ Ch, F16* __restrict__ Cl,
              const float* __restrict__ c2, float2* __restrict__ cand,
              int N, int K, int nbn)
{
    __shared__ __attribute__((aligned(16))) char smem[67584];
    v8h* As = (v8h*)smem;              // [2][1024] 32 KB
    v8h* Bs = (v8h*)(smem + 32768);    // [2][1024] 32 KB

    const int tid  = threadIdx.x;
    const int lane = tid & 63;
    const int wid  = tid >> 6;

    const int cpx = gridDim.x >> 3;
    const int sw  = (blockIdx.x & 7) * cpx + (blockIdx.x >> 3);
    const int mt  = sw / nbn;
    const int nt_ = sw - mt * nbn;
    const long bm = (long)mt * 128;
    const long bn = (long)nt_ * 128;

    // staging: wave w rows [32w,32w+32), 4 gload_lds per operand
    const int rr = lane >> 3;
    const int c  = (lane & 7) ^ rr;
    const F16* aS[4]; const F16* bS[4];
    int dOf[4];
    #pragma unroll
    for (int jj = 0; jj < 4; jj++) {
        int rloc = wid * 32 + jj * 8;
        long ag = bm + rloc + rr, bg = bn + rloc + rr;
        aS[jj] = (c < 4) ? (Ah + ag * (long)K + c * 8) : (Al + ag * (long)K + (c - 4) * 8);
        bS[jj] = (c < 4) ? (Bh + bg * (long)K + c * 8) : (Bl + bg * (long)K + (c - 4) * 8);
        dOf[jj] = rloc * 8;
    }

    const int cq = lane >> 4;
    const int wr = wid >> 1, wc = wid & 1;
    int aOff[4], bOff[4];
    #pragma unroll
    for (int i = 0; i < 4; i++) {
        int am  = wr * 64 + i * 16 + (lane & 15);
        aOff[i] = am * 8 + (cq ^ (am & 7));
        int bn2 = wc * 64 + i * 16 + (lane & 15);
        bOff[i] = bn2 * 8 + (cq ^ (bn2 & 7));
    }

    v4f acc[4][4]  = {};
    v4f accx[4][4] = {};

    auto stage = [&](int buf, int k0) {
        v8h* Ab = As + buf * 1024;
        v8h* Bb = Bs + buf * 1024;
        #pragma unroll
        for (int jj = 0; jj < 4; jj++) gload_lds16(aS[jj] + k0, Ab + dOf[jj]);
        #pragma unroll
        for (int jj = 0; jj < 4; jj++) gload_lds16(bS[jj] + k0, Bb + dOf[jj]);
    };

    const int nsteps = K >> 5;
    stage(0, 0);

    for (int t = 0; t < nsteps; ++t) {
        const int cur = t & 1;
        if (t + 1 < nsteps) {
            stage(cur ^ 1, (t + 1) * 32);
            asm volatile("s_waitcnt vmcnt(8)" ::: "memory");  // prev tile landed
        } else {
            asm volatile("s_waitcnt vmcnt(0)" ::: "memory");
        }
        __builtin_amdgcn_sched_barrier(0);
        __builtin_amdgcn_s_barrier();                          // buf[cur] ready
        __builtin_amdgcn_sched_barrier(0);

        const v8h* Ab = As + cur * 1024;
        const v8h* Bb = Bs + cur * 1024;
        v8h ah[4], al[4], bh[4], bl[4];
        // R0: operands for cluster (mi 0-1, ni 0-1)
        ah[0] = Ab[aOff[0]]; al[0] = Ab[aOff[0] ^ 4];
        ah[1] = Ab[aOff[1]]; al[1] = Ab[aOff[1] ^ 4];
        bh[0] = Bb[bOff[0]]; bl[0] = Bb[bOff[0] ^ 4];
        bh[1] = Bb[bOff[1]]; bl[1] = Bb[bOff[1] ^ 4];
        __builtin_amdgcn_sched_barrier(0);
        // R1: remaining B
        bh[2] = Bb[bOff[2]]; bl[2] = Bb[bOff[2] ^ 4];
        bh[3] = Bb[bOff[3]]; bl[3] = Bb[bOff[3] ^ 4];
        __builtin_amdgcn_sched_barrier(0);
        CLUSTER(0, 1, 0, 1)                                    // waits R0 only
        // R2: remaining A (hides under next cluster's window)
        ah[2] = Ab[aOff[2]]; al[2] = Ab[aOff[2] ^ 4];
        ah[3] = Ab[aOff[3]]; al[3] = Ab[aOff[3] ^ 4];
        __builtin_amdgcn_sched_barrier(0);
        CLUSTER(0, 1, 2, 3)                                    // waits R1
        CLUSTER(2, 3, 0, 1)                                    // waits R2
        CLUSTER(2, 3, 2, 3)
        __builtin_amdgcn_s_barrier();                          // release buf[cur]
        __builtin_amdgcn_sched_barrier(0);
    }

    const int cl = lane & 15;
    const int rb = (lane >> 4) * 4;

    if constexpr (OUT == 3) {
        // ---- fused argmin epilogue: dist = c2[code] - 2*s ----
        float* cD = (float*)smem;
        int*   cI = (int*)(smem + 1024);
        float bd[4][4]; int bi[4][4];
        #pragma unroll
        for (int mi = 0; mi < 4; mi++)
            #pragma unroll
            for (int r = 0; r < 4; r++) {
                float bb = 3.4e38f; int ii = 0;
                #pragma unroll
                for (int ni = 0; ni < 4; ni++) {
                    int code = (int)bn + wc * 64 + ni * 16 + cl;
                    float s  = acc[mi][ni][r] + accx[mi][ni][r] * (1.0f / 2048.0f);
                    float d  = fmaf(-2.0f, s, c2[code]);
                    if (d < bb || (d == bb && code < ii)) { bb = d; ii = code; }
                }
                bd[mi][r] = bb; bi[mi][r] = ii;
            }
        #pragma unroll
        for (int off = 1; off < 16; off <<= 1)
            #pragma unroll
            for (int mi = 0; mi < 4; mi++)
                #pragma unroll
                for (int r = 0; r < 4; r++) {
                    float od = __shfl_xor(bd[mi][r], off);
                    int   oi = __shfl_xor(bi[mi][r], off);
                    if (od < bd[mi][r] || (od == bd[mi][r] && oi < bi[mi][r])) {
                        bd[mi][r] = od; bi[mi][r] = oi;
                    }
                }
        if (cl == 0)
            #pragma unroll
            for (int mi = 0; mi < 4; mi++)
                #pragma unroll
                for (int r = 0; r < 4; r++) {
                    int rl = wr * 64 + mi * 16 + rb + r;
                    cD[rl * 2 + wc] = bd[mi][r];
                    cI[rl * 2 + wc] = bi[mi][r];
                }
        __syncthreads();
        if (tid < 128) {
            float d0 = cD[tid * 2], d1 = cD[tid * 2 + 1];
            int   i0 = cI[tid * 2], i1 = cI[tid * 2 + 1];
            float pd; int pk;
            if (d1 < d0 || (d1 == d0 && i1 < i0)) { pd = d1; pk = i1; }
            else                                  { pd = d0; pk = i0; }
            float2 out; out.x = pd; out.y = __int_as_float(pk);
            cand[(bm + tid) * 2 + (bn >> 7)] = out;
        }
    } else {
        // ---- LDS-transpose epilogue: coalesced wide stores ----
        float* sC = (float*)smem;    // stride 132
        #pragma unroll
        for (int mi = 0; mi < 4; mi++)
            #pragma unroll
            for (int ni = 0; ni < 4; ni++)
                #pragma unroll
                for (int r = 0; r < 4; r++)
                    sC[(wr * 64 + mi * 16 + rb + r) * 132 + wc * 64 + ni * 16 + cl] =
                        acc[mi][ni][r] + accx[mi][ni][r] * (1.0f / 2048.0f);
        __syncthreads();
        const int trow = tid >> 5;
        const int tcol = (tid & 31) << 2;
        float4 bv = {0.f, 0.f, 0.f, 0.f};
        if constexpr (HASBIAS) bv = *reinterpret_cast<const float4*>(bias + bn + tcol);
        #pragma unroll
        for (int it = 0; it < 16; ++it) {
            int row = trow + it * 8;
            float4 v = *reinterpret_cast<const float4*>(&sC[row * 132 + tcol]);
            v.x += bv.x; v.y += bv.y; v.z += bv.z; v.w += bv.w;
            if constexpr (RELU) {
                v.x = fmaxf(v.x, 0.f); v.y = fmaxf(v.y, 0.f);
                v.z = fmaxf(v.z, 0.f); v.w = fmaxf(v.w, 0.f);
            }
            long gr = (bm + row) * (long)N + bn + tcol;
            if constexpr (OUT == 0 || OUT == 2)
                *reinterpret_cast<float4*>(C + gr) = v;
            if constexpr (OUT == 1 || OUT == 2) {
                v4h h4, l4; F16 h, l;
                split2(v.x, h, l); h4[0] = h; l4[0] = l;
                split2(v.y, h, l); h4[1] = h; l4[1] = l;
                split2(v.z, h, l); h4[2] = h; l4[2] = l;
                split2(v.w, h, l); h4[3] = h; l4[3] = l;
                *reinterpret_cast<v4h*>(Ch + gr) = h4;
                *reinterpret_cast<v4h*>(Cl + gr) = l4;
            }
        }
    }
}

// W: K x N fp32 -> H/L: N x K f16 split (transpose + split).
__device__ __forceinline__ void wprep_task(const float* __restrict__ W,
                                           F16* __restrict__ H, F16* __restrict__ L,
                                           int K, int N, int idx, int stride, int total)
{
    for (int i = idx; i < total; i += stride) {
        int k = i / N, n = i - k * N;
        float v = W[i];
        F16 h, l; split2(v, h, l);
        H[(long)n * K + k] = h;
        L[(long)n * K + k] = l;
    }
}

// All launch-time prep in ONE dispatch: x split, 5 weight splits, codebook
// split, c2 table (exact float4 chain), loss-accumulator zero.
__global__ __launch_bounds__(256)
void prep_all(const float* __restrict__ x,
              const float* __restrict__ ew0, const float* __restrict__ ew1,
              const float* __restrict__ ew2, const float* __restrict__ dw0,
              const float* __restrict__ dw1, const float* __restrict__ cball,
              F16* __restrict__ Xh, F16* __restrict__ Xl,
              F16* __restrict__ e0h, F16* __restrict__ e0l,
              F16* __restrict__ e1h, F16* __restrict__ e1l,
              F16* __restrict__ e2h, F16* __restrict__ e2l,
              F16* __restrict__ d0h, F16* __restrict__ d0l,
              F16* __restrict__ d1h, F16* __restrict__ d1l,
              F16* __restrict__ cbh, F16* __restrict__ cbl,
              float* __restrict__ c2all, float* __restrict__ F)
{
    const int b = blockIdx.x, t = threadIdx.x;
    if (b < 3072) {
        for (long i = (long)b * 256 + t; i < 12582912; i += 786432) {
            float4 v = reinterpret_cast<const float4*>(x)[i];
            v4h h4, l4; F16 h, l;
            split2(v.x, h, l); h4[0] = h; l4[0] = l;
            split2(v.y, h, l); h4[1] = h; l4[1] = l;
            split2(v.z, h, l); h4[2] = h; l4[2] = l;
            split2(v.w, h, l); h4[3] = h; l4[3] = l;
            reinterpret_cast<v4h*>(Xh)[i] = h4;
            reinterpret_cast<v4h*>(Xl)[i] = l4;
        }
    } else if (b < 3584) wprep_task(ew0, e0h, e0l, 768, 512, (b - 3072) * 256 + t, 131072, 393216);
    else if (b < 3712)   wprep_task(ew1, e1h, e1l, 512, 256, (b - 3584) * 256 + t, 32768, 131072);
    else if (b < 3744)   wprep_task(ew2, e2h, e2l, 256, 128, (b - 3712) * 256 + t, 8192, 32768);
    else if (b < 3776)   wprep_task(dw0, d0h, d0l, 128, 256, (b - 3744) * 256 + t, 8192, 32768);
    else if (b < 3904)   wprep_task(dw1, d1h, d1l, 256, 512, (b - 3776) * 256 + t, 32768, 131072);
    else if (b < 4032) {
        for (int i = (b - 3904) * 256 + t; i < 131072; i += 32768) {
            float v = cball[i];
            F16 h, l; split2(v, h, l);
            cbh[i] = h; cbl[i] = l;
        }
    } else if (b < 4036) {
        int i = (b - 4032) * 256 + t;      // 0..1023 = level*256 + code
        const float* row = cball + (long)i * 128;
        float s = 0.f;
        #pragma unroll
        for (int d = 0; d < 128; d += 4) {
            float4 v = *reinterpret_cast<const float4*>(row + d);
            s += v.x * v.x + v.y * v.y + v.z * v.z + v.w * v.w;
        }
        c2all[i] = s;
    } else {
        if (t < 4) F[t] = 0.f;
    }
}

// standalone wprep for dec_w2 (runs after dec1 frees its ws region)
__global__ void wprep_kernel(const float* __restrict__ W, F16* __restrict__ H,
                             F16* __restrict__ L, int K, int N)
{
    int i = blockIdx.x * 256 + threadIdx.x;
    if (i >= K * N) return;
    wprep_task(W, H, L, K, N, i, K * N, i + 1);
}

// Per-row: pick winner from 2 candidate halves (tiebreak lower idx, matching
// jnp.argmin). Residual state lives ONLY as split f16 (rh + rl/2048,
// ~2^-22): update in place, accumulate SSE of the new residual
// (loss_l = 1.25*mean(resid_{l+1}^2)). Last level: x_q = z - resid_new,
// written as split for the decoder.
__global__ __launch_bounds__(256)
void rq_update3(const float2* __restrict__ cand,
                const float* __restrict__ cb,      // this level, fp32 [256][128]
                F16* __restrict__ rh, F16* __restrict__ rl,
                const float* __restrict__ z,       // pristine fp32 (last level)
                F16* __restrict__ xqh, F16* __restrict__ xql,
                float* __restrict__ lossF,
                int M, int last)
{
    __shared__ float lsum[4];
    const int tid  = threadIdx.x;
    const int lane = tid & 63;
    const int wave = tid >> 6;

    float myloss = 0.f;
    const int stride = gridDim.x * 4;
    for (int row = blockIdx.x * 4 + wave; row < M; row += stride) {
        float2 c0 = cand[(long)row * 2];
        float2 c1 = cand[(long)row * 2 + 1];
        int i0 = __float_as_int(c0.y), i1 = __float_as_int(c1.y);
        int bidx = (c1.x < c0.x || (c1.x == c0.x && i1 < i0)) ? i1 : i0;

        long base = (long)row * 128 + lane * 2;
        v2h hr = *reinterpret_cast<const v2h*>(rh + base);
        v2h lr = *reinterpret_cast<const v2h*>(rl + base);
        float rx = (float)hr[0] + (float)lr[0] * (1.0f / 2048.0f);
        float ry = (float)hr[1] + (float)lr[1] * (1.0f / 2048.0f);
        float2 q = *reinterpret_cast<const float2*>(cb + (long)bidx * 128 + lane * 2);
        float dx = rx - q.x, dy = ry - q.y;
        myloss += dx * dx + dy * dy;

        v2h nh, nl; F16 h, l;
        if (!last) {
            split2(dx, h, l); nh[0] = h; nl[0] = l;
            split2(dy, h, l); nh[1] = h; nl[1] = l;
            *reinterpret_cast<v2h*>(rh + base) = nh;
            *reinterpret_cast<v2h*>(rl + base) = nl;
        } else {
            float2 zv = *reinterpret_cast<const float2*>(z + base);
            split2(zv.x - dx, h, l); nh[0] = h; nl[0] = l;
            split2(zv.y - dy, h, l); nh[1] = h; nl[1] = l;
            *reinterpret_cast<v2h*>(xqh + base) = nh;
            *reinterpret_cast<v2h*>(xql + base) = nl;
        }
    }

    #pragma unroll
    for (int off = 32; off > 0; off >>= 1) myloss += __shfl_down(myloss, off);
    if (lane == 0) lsum[wave] = myloss;
    __syncthreads();
    if (tid == 0) atomicAdd(lossF, (lsum[0] + lsum[1]) + (lsum[2] + lsum[3]));
}

__global__ void finalize_loss_kernel(const float* __restrict__ F, float* __restrict__ out)
{
    if (threadIdx.x == 0) {
        float s = (F[0] + F[1]) + (F[2] + F[3]);
        out[0] = s * (1.25f / (4.f * 65536.f * 128.f));
    }
}

extern "C" void kernel_launch(void* const* d_in, const int* in_sizes, int n_in,
                              void* d_out, int out_size, void* d_ws, size_t ws_size,
                              hipStream_t stream)
{
    const float* x      = (const float*)d_in[0];
    const float* enc_w0 = (const float*)d_in[1];
    const float* enc_b0 = (const float*)d_in[2];
    const float* enc_w1 = (const float*)d_in[3];
    const float* enc_b1 = (const float*)d_in[4];
    const float* enc_w2 = (const float*)d_in[5];
    const float* enc_b2 = (const float*)d_in[6];
    const float* dec_w0 = (const float*)d_in[7];
    const float* dec_b0 = (const float*)d_in[8];
    const float* dec_w1 = (const float*)d_in[9];
    const float* dec_b1 = (const float*)d_in[10];
    const float* dec_w2 = (const float*)d_in[11];
    const float* dec_b2 = (const float*)d_in[12];
    const float* codebooks = (const float*)d_in[13];

    const int M = 65536;

    // ws overlay (201.3 MB = 100,663,296 f16):
    //   Xh [0,50.3M) Xl [50.3M,100.7M)        (dead after enc0)
    //   z f32[0,8.4M)  zh f16[16.8M,25.2M)  zl [25.2M,33.5M)  (z stays pristine;
    //     zh/zl become the running resid split, updated in place)
    //   g2l [0,33.5M)  g2h [33.5M,67.1M)       (dec1 out)
    //   h2h [67.1M,83.9M) h2l [83.9M,100.7M) -> g1h/g1l -> d2h/d2l
    F16*   wsF = (F16*)d_ws;
    float* wsf = (float*)d_ws;
    F16*   Xh  = wsF;
    F16*   Xl  = wsF + 50331648;
    float* z   = wsf;
    F16*   zh  = wsF + 16777216;
    F16*   zl  = wsF + 25165824;
    F16*   g2l = wsF;
    F16*   g2h = wsF + 33554432;
    F16*   h2h = wsF + 67108864;
    F16*   h2l = wsF + 83886080;
    F16*   g1h = wsF + 67108864;
    F16*   g1l = wsF + 83886080;
    F16*   d2h = wsF + 67108864;
    F16*   d2l = d2h + 393216;

    // d_out overlay:
    //   h1h f16[0,33.5M) h1l [33.5M,67.1M)     (dead after enc1)
    //   xqh f16[16.8M,25.2M) xql [25.2M,33.5M)  (written at rq level 3)
    //   arena @ f16 67,108,864: weight splits | cand | c2all | F  (dead pre-dec2)
    //   y f32[0,50331648) + loss @ [50331648]
    F16*   doF = (F16*)d_out;
    float* y   = (float*)d_out;
    F16*   h1h = doF;
    F16*   h1l = doF + 33554432;
    F16*   xqh = doF + 16777216;
    F16*   xql = doF + 25165824;
    F16* e0h = doF + 67108864;  F16* e0l = e0h + 393216;
    F16* e1h = e0l + 393216;    F16* e1l = e1h + 131072;
    F16* e2h = e1l + 131072;    F16* e2l = e2h + 32768;
    F16* d0h = e2l + 32768;     F16* d0l = d0h + 32768;
    F16* d1h = d0l + 32768;     F16* d1l = d1h + 131072;
    F16* cbh = d1l + 131072;    F16* cbl = cbh + 131072;
    float2* cand  = (float2*)(doF + 68812800);            // 65536 x 2
    float*  c2all = (float*)(doF + 69337088);             // 1024
    float*  F     = c2all + 1024;

    dim3 blk(256);

    prep_all<<<dim3(4037), blk, 0, stream>>>(x, enc_w0, enc_w1, enc_w2, dec_w0, dec_w1,
                                             codebooks, Xh, Xl, e0h, e0l, e1h, e1l,
                                             e2h, e2l, d0h, d0l, d1h, d1l, cbh, cbl,
                                             c2all, F);

    // ---- encoder ----
    f16gemm3<1, true,  true><<<dim3(2048), blk, 0, stream>>>(Xh, Xl, e0h, e0l, enc_b0, nullptr, h1h, h1l, nullptr, nullptr, 512, 768, 4);
    f16gemm3<1, true,  true><<<dim3(1024), blk, 0, stream>>>(h1h, h1l, e1h, e1l, enc_b1, nullptr, h2h, h2l, nullptr, nullptr, 256, 512, 2);
    f16gemm3<2, false, true><<<dim3(512),  blk, 0, stream>>>(h2h, h2l, e2h, e2l, enc_b2, z, zh, zl, nullptr, nullptr, 128, 256, 1);

    // ---- residual quantization (resid split in zh/zl, in place) ----
    for (int l = 0; l < 4; l++) {
        const float* cb = codebooks + (long)l * 32768;
        f16gemm3<3, false, false><<<dim3(1024), blk, 0, stream>>>(zh, zl, cbh + l * 32768, cbl + l * 32768,
                                                                  nullptr, nullptr, nullptr, nullptr,
                                                                  c2all + l * 256, cand, 256, 128, 2);
        rq_update3<<<dim3(1024), blk, 0, stream>>>(cand, cb, zh, zl, z, xqh, xql,
                                                   F + l, M, (l == 3) ? 1 : 0);
    }
    finalize_loss_kernel<<<dim3(1), dim3(64), 0, stream>>>(F, y + 50331648);

    // ---- decoder (y_q == x_q numerically) ----
    f16gemm3<1, true,  true><<<dim3(1024), blk, 0, stream>>>(xqh, xql, d0h, d0l, dec_b0, nullptr, g1h, g1l, nullptr, nullptr, 256, 128, 2);
    f16gemm3<1, true,  true><<<dim3(2048), blk, 0, stream>>>(g1h, g1l, d1h, d1l, dec_b1, nullptr, g2h, g2l, nullptr, nullptr, 512, 256, 4);
    wprep_kernel<<<dim3(1536), blk, 0, stream>>>(dec_w2, d2h, d2l, 512, 768);
    f16gemm3<0, false, true><<<dim3(3072), blk, 0, stream>>>(g2h, g2l, d2h, d2l, dec_b2, y, nullptr, nullptr, nullptr, nullptr, 768, 512, 6);
}